// Round 10
// baseline (571.568 us; speedup 1.0000x reference)
//
#include <hip/hip_runtime.h>
#include <hip/hip_bf16.h>
#include <math.h>

#define N_NODES   100000
#define N_EDGES   3200000
#define IN_DIM    128
#define HID       64
#define OUT_DIM   10
#define N_GRAPHS  64

// Radix geometry: bucket = row >> 8 (256 rows/bucket), tile = 8192 edges.
// Every (tile,bucket) run is padded to 8-edge (64 B) alignment so no output
// line is shared between blocks (R9: unaligned 168 B runs -> 2.2x write amp).
#define BUCKET_SHIFT 8
#define BUCKET_ROWS  256
#define NBUCKET ((N_NODES + BUCKET_ROWS - 1) >> BUCKET_SHIFT)     // 391
#define TILE_EDGES 8192                                           // 1024 thr x 8
#define NTILES ((N_EDGES + TILE_EDGES - 1) / TILE_EDGES)          // 391
#define NH (NBUCKET * NTILES)                                     // 152,881
#define NSCAN1 ((NH + 1023) / 1024)                               // 150
#define EPAD (N_EDGES + 7 * NH)                                   // max padded slots

#define SENTINEL 0xFFFFFFFF00000000ull   // col bits = 0xFFFFFF -> pad slot

typedef unsigned long long ull;
typedef unsigned short ushort;
typedef __attribute__((ext_vector_type(8))) short short8;   // 8 bf16 (4 VGPRs)
typedef __attribute__((ext_vector_type(4))) float f32x4;    // MFMA C/D

__device__ __forceinline__ ushort rne_bf16(float x) {
    unsigned u = __float_as_uint(x);
    return (ushort)((u + 0x7fffu + ((u >> 16) & 1u)) >> 16);
}
__device__ __forceinline__ float bf2f(ushort u) {
    return __uint_as_float((unsigned)u << 16);
}

// ---------------------------------------------------------------- pass A
// Per-tile LDS histogram; write PADDED counts (roundup8) to histT[tile][bucket].
__global__ __launch_bounds__(1024) void hist_pass(const int* __restrict__ rows,
                                                  int* __restrict__ histT) {
    __shared__ int h[NBUCKET];
    int tid = threadIdx.x, tile = blockIdx.x;
    for (int i = tid; i < NBUCKET; i += 1024) h[i] = 0;
    __syncthreads();
    int base = tile * TILE_EDGES;
#pragma unroll
    for (int i = 0; i < 8; i++) {
        int e = base + i * 1024 + tid;
        if (e < N_EDGES) atomicAdd(&h[rows[e] >> BUCKET_SHIFT], 1);
    }
    __syncthreads();
    for (int i = tid; i < NBUCKET; i += 1024)
        histT[tile * NBUCKET + i] = (h[i] + 7) & ~7;
}

// ---------------------------------------------------------------- transpose
__global__ __launch_bounds__(1024) void transpose_int(const int* __restrict__ in,
                                                      int* __restrict__ out,
                                                      int R, int C) {
    __shared__ int tile[32][33];
    int tx = threadIdx.x, ty = threadIdx.y;
    int r = blockIdx.y * 32 + ty, c = blockIdx.x * 32 + tx;
    if (r < R && c < C) tile[ty][tx] = in[r * C + c];
    __syncthreads();
    int rr = blockIdx.y * 32 + tx, cc = blockIdx.x * 32 + ty;
    if (cc < C && rr < R) out[cc * R + rr] = tile[tx][ty];
}

// ---------------------------------------------------------------- scan
__global__ __launch_bounds__(256) void scan_blocks(const int* __restrict__ in,
                                                   int* __restrict__ out,
                                                   int* __restrict__ blk, int n) {
    __shared__ int sdata[256];
    int t = threadIdx.x;
    int base = blockIdx.x * 1024 + t * 4;
    int v[4];
#pragma unroll
    for (int i = 0; i < 4; i++) {
        int idx = base + i;
        v[i] = (idx < n) ? in[idx] : 0;
    }
    int s = v[0] + v[1] + v[2] + v[3];
    sdata[t] = s;
    __syncthreads();
    for (int off = 1; off < 256; off <<= 1) {
        int x = (t >= off) ? sdata[t - off] : 0;
        __syncthreads();
        sdata[t] += x;
        __syncthreads();
    }
    int excl = sdata[t] - s;
#pragma unroll
    for (int i = 0; i < 4; i++) {
        int idx = base + i;
        if (idx < n) { out[idx] = excl; excl += v[i]; }
    }
    if (t == 255) blk[blockIdx.x] = sdata[255];
}

__global__ __launch_bounds__(256) void scan_add(int* __restrict__ data,
                                                const int* __restrict__ blk, int n) {
    int i = blockIdx.x * 256 + threadIdx.x;
    if (i < n) data[i] += blk[i >> 10];
}

// ---------------------------------------------------------------- pass B
// Re-read edges; LDS cursors = PADDED offsets (cursorT[tile][bucket]); write
// bucket-grouped packed records (rowLocal(8b)<<56 | col<<32 | val). After the
// scatter, fill each run's pad slots (up to next 8-boundary) with SENTINEL.
// 64B-aligned runs -> no cross-block line sharing.
__global__ __launch_bounds__(1024) void scatter_pass(const int* __restrict__ rows,
                                                     const int* __restrict__ cols,
                                                     const float* __restrict__ vals,
                                                     const int* __restrict__ cursorT,
                                                     ull* __restrict__ etmp) {
    __shared__ int cur[NBUCKET];
    int tid = threadIdx.x, tile = blockIdx.x;
    for (int i = tid; i < NBUCKET; i += 1024) cur[i] = cursorT[tile * NBUCKET + i];
    __syncthreads();
    int base = tile * TILE_EDGES;
#pragma unroll
    for (int i = 0; i < 8; i++) {
        int e = base + i * 1024 + tid;
        if (e < N_EDGES) {
            int r = rows[e];
            int b = r >> BUCKET_SHIFT;
            int pos = atomicAdd(&cur[b], 1);      // LDS atomic, block-local
            unsigned hi = ((unsigned)(r & (BUCKET_ROWS - 1)) << 24) | (unsigned)cols[e];
            etmp[pos] = ((ull)hi << 32) | (ull)__float_as_uint(vals[e]);
        }
    }
    __syncthreads();
    // pad to the run's 8-aligned end (run start is 8-aligned by construction)
    for (int i = tid; i < NBUCKET; i += 1024) {
        int c = cur[i];
        int ce = (c + 7) & ~7;
        for (int j = c; j < ce; j++) etmp[j] = SENTINEL;
    }
}

// ---------------------------------------------------------------- pass C
// One 512-thr block per 256-row bucket: counting-sort the bucket's padded
// region (skipping SENTINELs) by local row; emit row_start/row_end and final
// packed edges (val<<32|col); zero-fill the bucket's tail gap so any slot in
// [0,EPAD) holds a finite (val,col) record.
__global__ __launch_bounds__(512) void bucket_sort(const int* __restrict__ histL,
                                                   const int* __restrict__ histC,
                                                   const ull* __restrict__ etmp,
                                                   ull* __restrict__ edges,
                                                   int* __restrict__ row_start,
                                                   int* __restrict__ row_end) {
    __shared__ int rcnt[BUCKET_ROWS];
    __shared__ int roff[BUCKET_ROWS];
    __shared__ int rcur[BUCKET_ROWS];
    int b = blockIdx.x, t = threadIdx.x;
    int s = histL[b * NTILES];
    int e = (b + 1 < NBUCKET) ? histL[(b + 1) * NTILES]
                              : histL[NH - 1] + histC[NH - 1];
    if (t < BUCKET_ROWS) rcnt[t] = 0;
    __syncthreads();
    for (int j = s + t; j < e; j += 512) {
        ull p = etmp[j];
        if (((unsigned)(p >> 32) & 0xFFFFFFu) != 0xFFFFFFu)
            atomicAdd(&rcnt[(int)(p >> 56)], 1);
    }
    __syncthreads();
    if (t < BUCKET_ROWS) roff[t] = rcnt[t];
    __syncthreads();
    for (int off = 1; off < BUCKET_ROWS; off <<= 1) {
        int x = (t >= off && t < BUCKET_ROWS) ? roff[t - off] : 0;
        __syncthreads();
        if (t < BUCKET_ROWS) roff[t] += x;
        __syncthreads();
    }
    if (t < BUCKET_ROWS) {
        int excl = roff[t] - rcnt[t];
        rcur[t] = s + excl;
        int grow = b * BUCKET_ROWS + t;
        if (grow < N_NODES) {
            row_start[grow] = s + excl;
            row_end[grow]   = s + excl + rcnt[t];
        }
    }
    __syncthreads();
    for (int j = s + t; j < e; j += 512) {
        ull p = etmp[j];
        if (((unsigned)(p >> 32) & 0xFFFFFFu) == 0xFFFFFFu) continue;
        int rl = (int)(p >> 56);
        unsigned col = (unsigned)(p >> 32) & 0xFFFFFFu;
        int pos = atomicAdd(&rcur[rl], 1);        // LDS atomic
        edges[pos] = ((p & 0xFFFFFFFFull) << 32) | (ull)col;
    }
    __syncthreads();
    // zero-fill the tail gap (padded size - real size): val=0, col=0 -> inert
    int realtot = roff[BUCKET_ROWS - 1];
    for (int j = s + realtot + t; j < e; j += 512) edges[j] = 0ull;
}

// ------------------------------------------------------------------- GEMM
// MFMA bf16: H[M,64] = X[M,K] @ W[64,K]^T + b, output bf16. X read once.
template <int K, typename XT>
__global__ __launch_bounds__(256) void gemm_mfma(const XT* __restrict__ X,
                                                 const float* __restrict__ W,
                                                 const float* __restrict__ B,
                                                 ushort* __restrict__ H) {
    constexpr int KS = K / 32;
    int wave = threadIdx.x >> 6;
    int lane = threadIdx.x & 63;
    int quad = lane >> 4;
    int l16  = lane & 15;
    int rowBase = blockIdx.x * 64 + wave * 16;
    int arow = rowBase + l16;
    if (arow > N_NODES - 1) arow = N_NODES - 1;   // clamp OOB loads (stores guarded)

    short8 a[KS];
#pragma unroll
    for (int ks = 0; ks < KS; ks++) {
        int k = ks * 32 + quad * 8;
        if constexpr (sizeof(XT) == 2) {
            a[ks] = *reinterpret_cast<const short8*>(X + (size_t)arow * K + k);
        } else {
            const float4* src = reinterpret_cast<const float4*>(X + (size_t)arow * K + k);
            float4 t0 = src[0], t1 = src[1];
            union { short8 v; ushort u[8]; } cv;
            cv.u[0] = rne_bf16(t0.x); cv.u[1] = rne_bf16(t0.y);
            cv.u[2] = rne_bf16(t0.z); cv.u[3] = rne_bf16(t0.w);
            cv.u[4] = rne_bf16(t1.x); cv.u[5] = rne_bf16(t1.y);
            cv.u[6] = rne_bf16(t1.z); cv.u[7] = rne_bf16(t1.w);
            a[ks] = cv.v;
        }
    }

    f32x4 acc[4];
#pragma unroll
    for (int nt = 0; nt < 4; nt++) acc[nt] = 0.f;

#pragma unroll
    for (int nt = 0; nt < 4; nt++) {
        int brow = nt * 16 + l16;                 // W row = output channel n
#pragma unroll
        for (int ks = 0; ks < KS; ks++) {
            int k = ks * 32 + quad * 8;
            const float4* src = reinterpret_cast<const float4*>(W + brow * K + k);
            float4 t0 = src[0], t1 = src[1];
            union { short8 v; ushort u[8]; } cv;
            cv.u[0] = rne_bf16(t0.x); cv.u[1] = rne_bf16(t0.y);
            cv.u[2] = rne_bf16(t0.z); cv.u[3] = rne_bf16(t0.w);
            cv.u[4] = rne_bf16(t1.x); cv.u[5] = rne_bf16(t1.y);
            cv.u[6] = rne_bf16(t1.z); cv.u[7] = rne_bf16(t1.w);
            acc[nt] = __builtin_amdgcn_mfma_f32_16x16x32_bf16(a[ks], cv.v, acc[nt], 0, 0, 0);
        }
    }

#pragma unroll
    for (int nt = 0; nt < 4; nt++) {
        int n = nt * 16 + l16;
        float bv = B[n];
#pragma unroll
        for (int reg = 0; reg < 4; reg++) {
            int m = rowBase + quad * 4 + reg;
            if (m < N_NODES) H[(size_t)m * HID + n] = rne_bf16(acc[nt][reg] + bv);
        }
    }
}

// ------------------------------------------------------------------- SpMM
// TWO rows per wave: lanes 0-31 = row 2w (feature pairs), lanes 32-63 =
// row 2w+1. Each gather is a uint (2 bf16 feats) -> 256 B per gather
// instruction across the wave (2x R9's 128 B), halving gather-instruction
// count at equal bytes. Per-lane predication (no tail loops); clamped
// out-of-range reads land on real or zero-filled slots (finite, v=0).
// Accumulation order per feature unchanged -> bitwise-identical results.
__global__ __launch_bounds__(256) void spmm_relu(const int* __restrict__ row_start,
                                                 const int* __restrict__ row_end,
                                                 const ull* __restrict__ edges,
                                                 const ushort* __restrict__ Hin,
                                                 ushort* __restrict__ Xout) {
    int wv = (blockIdx.x * 256 + threadIdx.x) >> 6;
    int r0 = wv * 2;
    if (r0 >= N_NODES) return;
    int lane = threadIdx.x & 63;
    int l = lane & 31;                 // feature pair index (feats 2l, 2l+1)
    int r = r0 + (lane >> 5);          // N_NODES even -> always valid
    int start = row_start[r];          // broadcast within each half-wave
    int end   = row_end[r];
    int len = end - start;
    int olen = __shfl_xor(len, 32);    // sibling half's length
    int nmax = len > olen ? len : olen;
    const ushort* hrow = Hin + 2 * l;
    float acc0 = 0.f, acc1 = 0.f;
    for (int k = 0; k < nmax; k += 8) {
        ull p[8];
#pragma unroll
        for (int i = 0; i < 8; i++) {
            int e = start + k + i;
            int ec = e < end ? e : end - 1;
            if (ec < 0) ec = 0;
            p[i] = edges[ec];
        }
        unsigned hv[8];
#pragma unroll
        for (int i = 0; i < 8; i++) {
            int c = (int)(unsigned)(p[i] & 0xFFFFFFFFull);
            hv[i] = *reinterpret_cast<const unsigned*>(hrow + (size_t)c * HID);
        }
#pragma unroll
        for (int i = 0; i < 8; i++) {
            float v = (start + k + i < end) ? __uint_as_float((unsigned)(p[i] >> 32)) : 0.f;
            acc0 += v * __uint_as_float(hv[i] << 16);
            acc1 += v * __uint_as_float(hv[i] & 0xFFFF0000u);
        }
    }
    unsigned res = ((unsigned)rne_bf16(fmaxf(acc1, 0.f)) << 16)
                 |  (unsigned)rne_bf16(fmaxf(acc0, 0.f));
    *reinterpret_cast<unsigned*>(Xout + (size_t)r * HID + 2 * l) = res;
}

// ------------------------------------------------------------------- Pool
// Segmented pool over X1+X2+X3 (bf16): lane = feature; batch sorted ->
// one atomicAdd per segment per wave.
__global__ __launch_bounds__(256) void pool_fused(const ushort* __restrict__ X1,
                                                  const ushort* __restrict__ X2,
                                                  const ushort* __restrict__ X3,
                                                  const int* __restrict__ batch,
                                                  float* __restrict__ sums) {
    int lane = threadIdx.x & 63;
    int w = threadIdx.x >> 6;
    int n0 = blockIdx.x * 128 + w * 32;
    if (n0 >= N_NODES) return;
    int n1 = n0 + 32;
    if (n1 > N_NODES) n1 = N_NODES;
    int g_cur = __builtin_amdgcn_readfirstlane(batch[n0]);
    float acc = 0.f;
    for (int n = n0; n < n1; n++) {
        int g = __builtin_amdgcn_readfirstlane(batch[n]);
        if (g != g_cur) {
            atomicAdd(&sums[g_cur * HID + lane], acc);
            acc = 0.f; g_cur = g;
        }
        size_t base = (size_t)n * HID + lane;
        acc += bf2f(X1[base]) + bf2f(X2[base]) + bf2f(X3[base]);
    }
    atomicAdd(&sums[g_cur * HID + lane], acc);
}

// ------------------------------------------------------------------- Head
__global__ __launch_bounds__(64) void head_kernel(const float* __restrict__ sums,
                                                  const int* __restrict__ batch,
                                                  const float* __restrict__ Wout,
                                                  const float* __restrict__ bout,
                                                  float* __restrict__ out) {
    int g = blockIdx.x;
    int t = threadIdx.x;
    __shared__ float pr[HID];
    __shared__ float lg[OUT_DIM];
    __shared__ float mx, sm;
    auto lb = [&](int key) {
        int lo = 0, hi = N_NODES;
        while (lo < hi) {
            int mid = (lo + hi) >> 1;
            if (batch[mid] < key) lo = mid + 1; else hi = mid;
        }
        return lo;
    };
    int cnt = lb(g + 1) - lb(g);
    float denom = 3.0f * (float)(cnt > 1 ? cnt : 1);
    pr[t] = sums[g * HID + t] / denom;
    __syncthreads();
    if (t < OUT_DIM) {
        float a = bout[t];
        for (int k = 0; k < HID; k++) a += pr[k] * Wout[t * HID + k];
        lg[t] = a;
    }
    __syncthreads();
    if (t == 0) {
        float m = lg[0];
        for (int j = 1; j < OUT_DIM; j++) m = fmaxf(m, lg[j]);
        float s = 0.f;
        for (int j = 0; j < OUT_DIM; j++) s += expf(lg[j] - m);
        mx = m; sm = s;
    }
    __syncthreads();
    if (t < OUT_DIM) out[g * OUT_DIM + t] = expf(lg[t] - mx) / sm;
}

// ---------------------------------------------------------------- launcher
extern "C" void kernel_launch(void* const* d_in, const int* in_sizes, int n_in,
                              void* d_out, int out_size, void* d_ws, size_t ws_size,
                              hipStream_t stream) {
    const float* X    = (const float*)d_in[0];
    const float* vals = (const float*)d_in[1];
    const float* W1   = (const float*)d_in[2];
    const float* b1   = (const float*)d_in[3];
    const float* W2   = (const float*)d_in[4];
    const float* b2   = (const float*)d_in[5];
    const float* W3   = (const float*)d_in[6];
    const float* b3   = (const float*)d_in[7];
    const float* Wout = (const float*)d_in[8];
    const float* bout = (const float*)d_in[9];
    const int*   rows = (const int*)d_in[10];
    const int*   cols = (const int*)d_in[11];
    const int*   batch= (const int*)d_in[12];
    float* out = (float*)d_out;

    char* p = (char*)d_ws;
    auto carve = [&](size_t bytes) {
        void* q = (void*)p;
        p += (bytes + 255) & ~(size_t)255;
        return q;
    };
    ushort* h     = (ushort*)carve((size_t)N_NODES * HID * 2);
    ull*   etmp   = (ull*)  carve((size_t)EPAD * 8);        // 34.2 MB
    ull*   edges  = (ull*)  carve((size_t)EPAD * 8);        // 34.2 MB
    ushort* X3    = (ushort*)carve((size_t)N_NODES * HID * 2);
    int*   bufA   = (int*)  carve((size_t)NH * 4);   // histT / cursorT [tile][bucket]
    int*   bufB   = (int*)  carve((size_t)NH * 4);   // scanned offsets [bucket][tile]
    int*   bufC   = (int*)  carve((size_t)NH * 4);   // padded counts [bucket][tile]
    int*   row_start = (int*)carve((size_t)N_NODES * 4);
    int*   row_end   = (int*)carve((size_t)N_NODES * 4);
    int*   blkA   = (int*)  carve(1024 * 4);
    int*   blkB   = (int*)  carve(1024 * 4);
    float* sums   = (float*)carve(N_GRAPHS * HID * 4);
    // X1/X2 alias etmp: etmp is dead after bucket_sort, before spmm1 writes X1.
    ushort* X1 = (ushort*)etmp;
    ushort* X2 = X1 + (size_t)N_NODES * HID;
    (void)ws_size; (void)in_sizes; (void)n_in; (void)out_size;

    // ---- build: padded hist[tile][bucket] -> transpose (keep counts) ->
    //      scan -> transpose back -> aligned scatter -> per-bucket sort
    hist_pass<<<NTILES, 1024, 0, stream>>>(rows, bufA);
    transpose_int<<<dim3((NBUCKET + 31) / 32, (NTILES + 31) / 32), dim3(32, 32), 0, stream>>>(bufA, bufC, NTILES, NBUCKET);
    scan_blocks<<<NSCAN1, 256, 0, stream>>>(bufC, bufB, blkA, NH);
    scan_blocks<<<1, 256, 0, stream>>>(blkA, blkA, blkB, NSCAN1);
    scan_add<<<(NH + 255) / 256, 256, 0, stream>>>(bufB, blkA, NH);
    transpose_int<<<dim3((NTILES + 31) / 32, (NBUCKET + 31) / 32), dim3(32, 32), 0, stream>>>(bufB, bufA, NBUCKET, NTILES);
    scatter_pass<<<NTILES, 1024, 0, stream>>>(rows, cols, vals, bufA, etmp);
    bucket_sort<<<NBUCKET, 512, 0, stream>>>(bufB, bufC, etmp, edges, row_start, row_end);

    const int gemm_grid = (N_NODES + 63) / 64;        // 64 rows/block
    const int spmm_grid = (N_NODES / 2 + 3) / 4;      // 2 rows/wave, 4 waves/block

    // ---- layers (X_l kept separately; pooling sums them later)
    gemm_mfma<IN_DIM, float><<<gemm_grid, 256, 0, stream>>>(X, W1, b1, h);
    spmm_relu<<<spmm_grid, 256, 0, stream>>>(row_start, row_end, edges, h, X1);
    gemm_mfma<HID, ushort><<<gemm_grid, 256, 0, stream>>>(X1, W2, b2, h);
    spmm_relu<<<spmm_grid, 256, 0, stream>>>(row_start, row_end, edges, h, X2);
    gemm_mfma<HID, ushort><<<gemm_grid, 256, 0, stream>>>(X2, W3, b3, h);
    spmm_relu<<<spmm_grid, 256, 0, stream>>>(row_start, row_end, edges, h, X3);

    // ---- pool + head
    hipMemsetAsync(sums, 0, N_GRAPHS * HID * 4, stream);
    pool_fused<<<(N_NODES + 127) / 128, 256, 0, stream>>>(X1, X2, X3, batch, sums);
    head_kernel<<<N_GRAPHS, 64, 0, stream>>>(sums, batch, Wout, bout, out);
}

// Round 11
// 500.888 us; speedup vs baseline: 1.1411x; 1.1411x over previous
//
#include <hip/hip_runtime.h>
#include <hip/hip_bf16.h>
#include <math.h>

#define N_NODES   100000
#define N_EDGES   3200000
#define IN_DIM    128
#define HID       64
#define OUT_DIM   10
#define N_GRAPHS  64

// Radix geometry: bucket = row >> 8 (256 rows/bucket), tile = 8192 edges.
// Every (tile,bucket) run is padded to 8-edge (64 B) alignment so no output
// line is shared between blocks (R9: unaligned 168 B runs -> 2.2x write amp).
#define BUCKET_SHIFT 8
#define BUCKET_ROWS  256
#define NBUCKET ((N_NODES + BUCKET_ROWS - 1) >> BUCKET_SHIFT)     // 391
#define TILE_EDGES 8192                                           // 1024 thr x 8
#define NTILES ((N_EDGES + TILE_EDGES - 1) / TILE_EDGES)          // 391
#define NH (NBUCKET * NTILES)                                     // 152,881
#define NSCAN1 ((NH + 1023) / 1024)                               // 150
#define EPAD (N_EDGES + 7 * NH)                                   // max padded slots

#define SENTINEL 0xFFFFFFFF00000000ull   // col bits = 0xFFFFFF -> pad slot

typedef unsigned long long ull;
typedef unsigned short ushort;
typedef __attribute__((ext_vector_type(8))) short short8;   // 8 bf16 (4 VGPRs)
typedef __attribute__((ext_vector_type(4))) float f32x4;    // MFMA C/D

__device__ __forceinline__ ushort rne_bf16(float x) {
    unsigned u = __float_as_uint(x);
    return (ushort)((u + 0x7fffu + ((u >> 16) & 1u)) >> 16);
}
__device__ __forceinline__ float bf2f(ushort u) {
    return __uint_as_float((unsigned)u << 16);
}

// ---------------------------------------------------------------- pass A
// Per-tile LDS histogram; write PADDED counts (roundup8) to histT[tile][bucket].
__global__ __launch_bounds__(1024) void hist_pass(const int* __restrict__ rows,
                                                  int* __restrict__ histT) {
    __shared__ int h[NBUCKET];
    int tid = threadIdx.x, tile = blockIdx.x;
    for (int i = tid; i < NBUCKET; i += 1024) h[i] = 0;
    __syncthreads();
    int base = tile * TILE_EDGES;
#pragma unroll
    for (int i = 0; i < 8; i++) {
        int e = base + i * 1024 + tid;
        if (e < N_EDGES) atomicAdd(&h[rows[e] >> BUCKET_SHIFT], 1);
    }
    __syncthreads();
    for (int i = tid; i < NBUCKET; i += 1024)
        histT[tile * NBUCKET + i] = (h[i] + 7) & ~7;
}

// ---------------------------------------------------------------- transpose
__global__ __launch_bounds__(1024) void transpose_int(const int* __restrict__ in,
                                                      int* __restrict__ out,
                                                      int R, int C) {
    __shared__ int tile[32][33];
    int tx = threadIdx.x, ty = threadIdx.y;
    int r = blockIdx.y * 32 + ty, c = blockIdx.x * 32 + tx;
    if (r < R && c < C) tile[ty][tx] = in[r * C + c];
    __syncthreads();
    int rr = blockIdx.y * 32 + tx, cc = blockIdx.x * 32 + ty;
    if (cc < C && rr < R) out[cc * R + rr] = tile[tx][ty];
}

// ---------------------------------------------------------------- scan
__global__ __launch_bounds__(256) void scan_blocks(const int* __restrict__ in,
                                                   int* __restrict__ out,
                                                   int* __restrict__ blk, int n) {
    __shared__ int sdata[256];
    int t = threadIdx.x;
    int base = blockIdx.x * 1024 + t * 4;
    int v[4];
#pragma unroll
    for (int i = 0; i < 4; i++) {
        int idx = base + i;
        v[i] = (idx < n) ? in[idx] : 0;
    }
    int s = v[0] + v[1] + v[2] + v[3];
    sdata[t] = s;
    __syncthreads();
    for (int off = 1; off < 256; off <<= 1) {
        int x = (t >= off) ? sdata[t - off] : 0;
        __syncthreads();
        sdata[t] += x;
        __syncthreads();
    }
    int excl = sdata[t] - s;
#pragma unroll
    for (int i = 0; i < 4; i++) {
        int idx = base + i;
        if (idx < n) { out[idx] = excl; excl += v[i]; }
    }
    if (t == 255) blk[blockIdx.x] = sdata[255];
}

__global__ __launch_bounds__(256) void scan_add(int* __restrict__ data,
                                                const int* __restrict__ blk, int n) {
    int i = blockIdx.x * 256 + threadIdx.x;
    if (i < n) data[i] += blk[i >> 10];
}

// ---------------------------------------------------------------- pass B
// Re-read edges; LDS cursors = PADDED offsets (cursorT[tile][bucket]); write
// bucket-grouped packed records (rowLocal(8b)<<56 | col<<32 | val). After the
// scatter, fill each run's pad slots (up to next 8-boundary) with SENTINEL.
// 64B-aligned runs -> no cross-block line sharing.
__global__ __launch_bounds__(1024) void scatter_pass(const int* __restrict__ rows,
                                                     const int* __restrict__ cols,
                                                     const float* __restrict__ vals,
                                                     const int* __restrict__ cursorT,
                                                     ull* __restrict__ etmp) {
    __shared__ int cur[NBUCKET];
    int tid = threadIdx.x, tile = blockIdx.x;
    for (int i = tid; i < NBUCKET; i += 1024) cur[i] = cursorT[tile * NBUCKET + i];
    __syncthreads();
    int base = tile * TILE_EDGES;
#pragma unroll
    for (int i = 0; i < 8; i++) {
        int e = base + i * 1024 + tid;
        if (e < N_EDGES) {
            int r = rows[e];
            int b = r >> BUCKET_SHIFT;
            int pos = atomicAdd(&cur[b], 1);      // LDS atomic, block-local
            unsigned hi = ((unsigned)(r & (BUCKET_ROWS - 1)) << 24) | (unsigned)cols[e];
            etmp[pos] = ((ull)hi << 32) | (ull)__float_as_uint(vals[e]);
        }
    }
    __syncthreads();
    // pad to the run's 8-aligned end (run start is 8-aligned by construction)
    for (int i = tid; i < NBUCKET; i += 1024) {
        int c = cur[i];
        int ce = (c + 7) & ~7;
        for (int j = c; j < ce; j++) etmp[j] = SENTINEL;
    }
}

// ---------------------------------------------------------------- pass C
// One 512-thr block per 256-row bucket: counting-sort the bucket's padded
// region (skipping SENTINELs) by local row; emit row_start/row_end and final
// packed edges (val<<32|col); zero-fill the bucket's tail gap.
__global__ __launch_bounds__(512) void bucket_sort(const int* __restrict__ histL,
                                                   const int* __restrict__ histC,
                                                   const ull* __restrict__ etmp,
                                                   ull* __restrict__ edges,
                                                   int* __restrict__ row_start,
                                                   int* __restrict__ row_end) {
    __shared__ int rcnt[BUCKET_ROWS];
    __shared__ int roff[BUCKET_ROWS];
    __shared__ int rcur[BUCKET_ROWS];
    int b = blockIdx.x, t = threadIdx.x;
    int s = histL[b * NTILES];
    int e = (b + 1 < NBUCKET) ? histL[(b + 1) * NTILES]
                              : histL[NH - 1] + histC[NH - 1];
    if (t < BUCKET_ROWS) rcnt[t] = 0;
    __syncthreads();
    for (int j = s + t; j < e; j += 512) {
        ull p = etmp[j];
        if (((unsigned)(p >> 32) & 0xFFFFFFu) != 0xFFFFFFu)
            atomicAdd(&rcnt[(int)(p >> 56)], 1);
    }
    __syncthreads();
    if (t < BUCKET_ROWS) roff[t] = rcnt[t];
    __syncthreads();
    for (int off = 1; off < BUCKET_ROWS; off <<= 1) {
        int x = (t >= off && t < BUCKET_ROWS) ? roff[t - off] : 0;
        __syncthreads();
        if (t < BUCKET_ROWS) roff[t] += x;
        __syncthreads();
    }
    if (t < BUCKET_ROWS) {
        int excl = roff[t] - rcnt[t];
        rcur[t] = s + excl;
        int grow = b * BUCKET_ROWS + t;
        if (grow < N_NODES) {
            row_start[grow] = s + excl;
            row_end[grow]   = s + excl + rcnt[t];
        }
    }
    __syncthreads();
    for (int j = s + t; j < e; j += 512) {
        ull p = etmp[j];
        if (((unsigned)(p >> 32) & 0xFFFFFFu) == 0xFFFFFFu) continue;
        int rl = (int)(p >> 56);
        unsigned col = (unsigned)(p >> 32) & 0xFFFFFFu;
        int pos = atomicAdd(&rcur[rl], 1);        // LDS atomic
        edges[pos] = ((p & 0xFFFFFFFFull) << 32) | (ull)col;
    }
    __syncthreads();
    // zero-fill the tail gap (padded size - real size): val=0, col=0 -> inert
    int realtot = roff[BUCKET_ROWS - 1];
    for (int j = s + realtot + t; j < e; j += 512) edges[j] = 0ull;
}

// ------------------------------------------------------------------- GEMM
// MFMA bf16: H[M,64] = X[M,K] @ W[64,K]^T + b, output bf16. X read once.
template <int K, typename XT>
__global__ __launch_bounds__(256) void gemm_mfma(const XT* __restrict__ X,
                                                 const float* __restrict__ W,
                                                 const float* __restrict__ B,
                                                 ushort* __restrict__ H) {
    constexpr int KS = K / 32;
    int wave = threadIdx.x >> 6;
    int lane = threadIdx.x & 63;
    int quad = lane >> 4;
    int l16  = lane & 15;
    int rowBase = blockIdx.x * 64 + wave * 16;
    int arow = rowBase + l16;
    if (arow > N_NODES - 1) arow = N_NODES - 1;   // clamp OOB loads (stores guarded)

    short8 a[KS];
#pragma unroll
    for (int ks = 0; ks < KS; ks++) {
        int k = ks * 32 + quad * 8;
        if constexpr (sizeof(XT) == 2) {
            a[ks] = *reinterpret_cast<const short8*>(X + (size_t)arow * K + k);
        } else {
            const float4* src = reinterpret_cast<const float4*>(X + (size_t)arow * K + k);
            float4 t0 = src[0], t1 = src[1];
            union { short8 v; ushort u[8]; } cv;
            cv.u[0] = rne_bf16(t0.x); cv.u[1] = rne_bf16(t0.y);
            cv.u[2] = rne_bf16(t0.z); cv.u[3] = rne_bf16(t0.w);
            cv.u[4] = rne_bf16(t1.x); cv.u[5] = rne_bf16(t1.y);
            cv.u[6] = rne_bf16(t1.z); cv.u[7] = rne_bf16(t1.w);
            a[ks] = cv.v;
        }
    }

    f32x4 acc[4];
#pragma unroll
    for (int nt = 0; nt < 4; nt++) acc[nt] = 0.f;

#pragma unroll
    for (int nt = 0; nt < 4; nt++) {
        int brow = nt * 16 + l16;                 // W row = output channel n
#pragma unroll
        for (int ks = 0; ks < KS; ks++) {
            int k = ks * 32 + quad * 8;
            const float4* src = reinterpret_cast<const float4*>(W + brow * K + k);
            float4 t0 = src[0], t1 = src[1];
            union { short8 v; ushort u[8]; } cv;
            cv.u[0] = rne_bf16(t0.x); cv.u[1] = rne_bf16(t0.y);
            cv.u[2] = rne_bf16(t0.z); cv.u[3] = rne_bf16(t0.w);
            cv.u[4] = rne_bf16(t1.x); cv.u[5] = rne_bf16(t1.y);
            cv.u[6] = rne_bf16(t1.z); cv.u[7] = rne_bf16(t1.w);
            acc[nt] = __builtin_amdgcn_mfma_f32_16x16x32_bf16(a[ks], cv.v, acc[nt], 0, 0, 0);
        }
    }

#pragma unroll
    for (int nt = 0; nt < 4; nt++) {
        int n = nt * 16 + l16;
        float bv = B[n];
#pragma unroll
        for (int reg = 0; reg < 4; reg++) {
            int m = rowBase + quad * 4 + reg;
            if (m < N_NODES) H[(size_t)m * HID + n] = rne_bf16(acc[nt][reg] + bv);
        }
    }
}

// ------------------------------------------------------------------- SpMM
// Row-per-wave (R9 structure, proven 55.6 us): wave-uniform row index via
// readfirstlane -> edge loads become SCALAR s_loads (SMEM path), leaving
// the vector-memory pipe exclusively for the 128 B bf16 gathers. R10's
// 2-rows-per-wave variant broke this property and regressed 54%.
__global__ __launch_bounds__(256) void spmm_relu(const int* __restrict__ row_start,
                                                 const int* __restrict__ row_end,
                                                 const ull* __restrict__ edges,
                                                 const ushort* __restrict__ Hin,
                                                 ushort* __restrict__ Xout) {
    int wid  = (blockIdx.x * 256 + threadIdx.x) >> 6;
    int lane = threadIdx.x & 63;
    if (wid >= N_NODES) return;
    int r = __builtin_amdgcn_readfirstlane(wid);  // wave-uniform -> s_loads
    int start = row_start[r];
    int end   = row_end[r];
    float acc = 0.f;
    int e = start;
    for (; e + 16 <= end; e += 16) {
        ull p[16];
#pragma unroll
        for (int i = 0; i < 16; i++) p[i] = edges[e + i];
        float h[16];
#pragma unroll
        for (int i = 0; i < 16; i++) {
            int c = (int)(unsigned)(p[i] & 0xFFFFFFFFull);
            h[i] = bf2f(Hin[c * HID + lane]);
        }
#pragma unroll
        for (int i = 0; i < 16; i++) {
            float v = __uint_as_float((unsigned)(p[i] >> 32));
            acc += v * h[i];
        }
    }
    for (; e + 4 <= end; e += 4) {
        ull p[4];
#pragma unroll
        for (int i = 0; i < 4; i++) p[i] = edges[e + i];
#pragma unroll
        for (int i = 0; i < 4; i++) {
            int c = (int)(unsigned)(p[i] & 0xFFFFFFFFull);
            float v = __uint_as_float((unsigned)(p[i] >> 32));
            acc += v * bf2f(Hin[c * HID + lane]);
        }
    }
    for (; e < end; e++) {
        ull p = edges[e];
        int c = (int)(unsigned)(p & 0xFFFFFFFFull);
        float v = __uint_as_float((unsigned)(p >> 32));
        acc += v * bf2f(Hin[c * HID + lane]);
    }
    Xout[(size_t)r * HID + lane] = rne_bf16(fmaxf(acc, 0.f));
}

// ------------------------------------------------------------------- Pool
// Segmented pool over X1+X2+X3 (bf16): lane = feature; batch sorted ->
// one atomicAdd per segment per wave.
__global__ __launch_bounds__(256) void pool_fused(const ushort* __restrict__ X1,
                                                  const ushort* __restrict__ X2,
                                                  const ushort* __restrict__ X3,
                                                  const int* __restrict__ batch,
                                                  float* __restrict__ sums) {
    int lane = threadIdx.x & 63;
    int w = threadIdx.x >> 6;
    int n0 = blockIdx.x * 128 + w * 32;
    if (n0 >= N_NODES) return;
    int n1 = n0 + 32;
    if (n1 > N_NODES) n1 = N_NODES;
    int g_cur = __builtin_amdgcn_readfirstlane(batch[n0]);
    float acc = 0.f;
    for (int n = n0; n < n1; n++) {
        int g = __builtin_amdgcn_readfirstlane(batch[n]);
        if (g != g_cur) {
            atomicAdd(&sums[g_cur * HID + lane], acc);
            acc = 0.f; g_cur = g;
        }
        size_t base = (size_t)n * HID + lane;
        acc += bf2f(X1[base]) + bf2f(X2[base]) + bf2f(X3[base]);
    }
    atomicAdd(&sums[g_cur * HID + lane], acc);
}

// ------------------------------------------------------------------- Head
__global__ __launch_bounds__(64) void head_kernel(const float* __restrict__ sums,
                                                  const int* __restrict__ batch,
                                                  const float* __restrict__ Wout,
                                                  const float* __restrict__ bout,
                                                  float* __restrict__ out) {
    int g = blockIdx.x;
    int t = threadIdx.x;
    __shared__ float pr[HID];
    __shared__ float lg[OUT_DIM];
    __shared__ float mx, sm;
    auto lb = [&](int key) {
        int lo = 0, hi = N_NODES;
        while (lo < hi) {
            int mid = (lo + hi) >> 1;
            if (batch[mid] < key) lo = mid + 1; else hi = mid;
        }
        return lo;
    };
    int cnt = lb(g + 1) - lb(g);
    float denom = 3.0f * (float)(cnt > 1 ? cnt : 1);
    pr[t] = sums[g * HID + t] / denom;
    __syncthreads();
    if (t < OUT_DIM) {
        float a = bout[t];
        for (int k = 0; k < HID; k++) a += pr[k] * Wout[t * HID + k];
        lg[t] = a;
    }
    __syncthreads();
    if (t == 0) {
        float m = lg[0];
        for (int j = 1; j < OUT_DIM; j++) m = fmaxf(m, lg[j]);
        float s = 0.f;
        for (int j = 0; j < OUT_DIM; j++) s += expf(lg[j] - m);
        mx = m; sm = s;
    }
    __syncthreads();
    if (t < OUT_DIM) out[g * OUT_DIM + t] = expf(lg[t] - mx) / sm;
}

// ---------------------------------------------------------------- launcher
extern "C" void kernel_launch(void* const* d_in, const int* in_sizes, int n_in,
                              void* d_out, int out_size, void* d_ws, size_t ws_size,
                              hipStream_t stream) {
    const float* X    = (const float*)d_in[0];
    const float* vals = (const float*)d_in[1];
    const float* W1   = (const float*)d_in[2];
    const float* b1   = (const float*)d_in[3];
    const float* W2   = (const float*)d_in[4];
    const float* b2   = (const float*)d_in[5];
    const float* W3   = (const float*)d_in[6];
    const float* b3   = (const float*)d_in[7];
    const float* Wout = (const float*)d_in[8];
    const float* bout = (const float*)d_in[9];
    const int*   rows = (const int*)d_in[10];
    const int*   cols = (const int*)d_in[11];
    const int*   batch= (const int*)d_in[12];
    float* out = (float*)d_out;

    char* p = (char*)d_ws;
    auto carve = [&](size_t bytes) {
        void* q = (void*)p;
        p += (bytes + 255) & ~(size_t)255;
        return q;
    };
    ushort* h     = (ushort*)carve((size_t)N_NODES * HID * 2);
    ull*   etmp   = (ull*)  carve((size_t)EPAD * 8);        // 34.2 MB
    ull*   edges  = (ull*)  carve((size_t)EPAD * 8);        // 34.2 MB
    ushort* X3    = (ushort*)carve((size_t)N_NODES * HID * 2);
    int*   bufA   = (int*)  carve((size_t)NH * 4);   // histT / cursorT [tile][bucket]
    int*   bufB   = (int*)  carve((size_t)NH * 4);   // scanned offsets [bucket][tile]
    int*   bufC   = (int*)  carve((size_t)NH * 4);   // padded counts [bucket][tile]
    int*   row_start = (int*)carve((size_t)N_NODES * 4);
    int*   row_end   = (int*)carve((size_t)N_NODES * 4);
    int*   blkA   = (int*)  carve(1024 * 4);
    int*   blkB   = (int*)  carve(1024 * 4);
    float* sums   = (float*)carve(N_GRAPHS * HID * 4);
    // X1/X2 alias etmp: etmp is dead after bucket_sort, before spmm1 writes X1.
    ushort* X1 = (ushort*)etmp;
    ushort* X2 = X1 + (size_t)N_NODES * HID;
    (void)ws_size; (void)in_sizes; (void)n_in; (void)out_size;

    // ---- build: padded hist[tile][bucket] -> transpose (keep counts) ->
    //      scan -> transpose back -> aligned scatter -> per-bucket sort
    hist_pass<<<NTILES, 1024, 0, stream>>>(rows, bufA);
    transpose_int<<<dim3((NBUCKET + 31) / 32, (NTILES + 31) / 32), dim3(32, 32), 0, stream>>>(bufA, bufC, NTILES, NBUCKET);
    scan_blocks<<<NSCAN1, 256, 0, stream>>>(bufC, bufB, blkA, NH);
    scan_blocks<<<1, 256, 0, stream>>>(blkA, blkA, blkB, NSCAN1);
    scan_add<<<(NH + 255) / 256, 256, 0, stream>>>(bufB, blkA, NH);
    transpose_int<<<dim3((NTILES + 31) / 32, (NBUCKET + 31) / 32), dim3(32, 32), 0, stream>>>(bufB, bufA, NBUCKET, NTILES);
    scatter_pass<<<NTILES, 1024, 0, stream>>>(rows, cols, vals, bufA, etmp);
    bucket_sort<<<NBUCKET, 512, 0, stream>>>(bufB, bufC, etmp, edges, row_start, row_end);

    const int gemm_grid = (N_NODES + 63) / 64;   // 64 rows/block
    const int spmm_grid = (N_NODES + 3) / 4;     // 1 row/wave, 4 waves/block

    // ---- layers (X_l kept separately; pooling sums them later)
    gemm_mfma<IN_DIM, float><<<gemm_grid, 256, 0, stream>>>(X, W1, b1, h);
    spmm_relu<<<spmm_grid, 256, 0, stream>>>(row_start, row_end, edges, h, X1);
    gemm_mfma<HID, ushort><<<gemm_grid, 256, 0, stream>>>(X1, W2, b2, h);
    spmm_relu<<<spmm_grid, 256, 0, stream>>>(row_start, row_end, edges, h, X2);
    gemm_mfma<HID, ushort><<<gemm_grid, 256, 0, stream>>>(X2, W3, b3, h);
    spmm_relu<<<spmm_grid, 256, 0, stream>>>(row_start, row_end, edges, h, X3);

    // ---- pool + head
    hipMemsetAsync(sums, 0, N_GRAPHS * HID * 4, stream);
    pool_fused<<<(N_NODES + 127) / 128, 256, 0, stream>>>(X1, X2, X3, batch, sums);
    head_kernel<<<N_GRAPHS, 64, 0, stream>>>(sums, batch, Wout, bout, out);
}